// Round 5
// baseline (470.324 us; speedup 1.0000x reference)
//
#include <hip/hip_runtime.h>
#include <math.h>

#define F_ 48
#define C_ 128
#define HW 16384
#define SCALE_C 0.999f
#define TPB 256      // setup kernels
#define MTPB 512     // main kernel: 8 waves/block

typedef __attribute__((ext_vector_type(4))) float floatx4;
typedef __attribute__((ext_vector_type(8))) _Float16 half8;
typedef __attribute__((ext_vector_type(4))) _Float16 half4;

// ---- ws layout ----
// ushort region:
//   P1 frags (f16): [mtile(24)][ks(4)][lane(64)][j(8)] = 49152 ushorts
//     even mtile = Wf rows (v), odd mtile = (Qeq.Wf) rows (y), paired per f-group
//   P2 frags (f16): [cmt(8)][ks(12)][lane(64)][j(8)] = 49152 ushorts at 49152
//     ks 0..5 = Wf^T (u part), ks 6..11 = -(SCALE*Qm)^T-folded Wf (m2 part)
// float region at float offset 49152 (byte 196608):
#define P1_U 0
#define P2_U 49152
#define QEQN_F 49152              // [48][32]: [0..15]=Qeq[l][g], [16..31]=SCALE*Qm[a][b]
#define MISC_F (QEQN_F + 1536)    // eps_e, invden
#define SINV_F (MISC_F + 2)       // [2][48] 1/scaling
#define SLAM_F (SINV_F + 96)      // [2][48] lamb_e*scaling

// ---------------- setup: math (1 block, tiny) ----------------
__global__ void setup_math(const float* __restrict__ sigma,
                           const float* __restrict__ Qp,
                           const float* __restrict__ taus_p,
                           const float* __restrict__ lamb,
                           const float* __restrict__ eps_om,
                           const float* __restrict__ mw1, const float* __restrict__ mb1,
                           const float* __restrict__ mw2, const float* __restrict__ mb2,
                           const float* __restrict__ mw3, const float* __restrict__ mb3,
                           float* __restrict__ wsf)
{
    const int tid = threadIdx.x;
    if (tid < F_) {
        const int f = tid;
        float Qm[4][4];
        for (int g = 0; g < 4; ++g) {
            float s = 0.f;
            for (int l = 0; l < 4; ++l) s += fabsf(Qp[f * 16 + g * 4 + l]);
            float d = fmaxf(s, 1.0f);
            for (int l = 0; l < 4; ++l) Qm[g][l] = Qp[f * 16 + g * 4 + l] / d;
        }
        double A[4][4];
        for (int i = 0; i < 4; ++i)
            for (int j = 0; j < 4; ++j) {
                double s = 0.0;
                for (int g = 0; g < 4; ++g) s += (double)Qm[g][i] * (double)Qm[g][j];
                A[i][j] = s;
            }
        double M[4][4];
        for (int i = 0; i < 4; ++i) for (int j = 0; j < 4; ++j) M[i][j] = A[i][j];
        for (int it = 0; it < 30; ++it) {
            double T[4][4]; double mx = 0.0;
            for (int i = 0; i < 4; ++i)
                for (int j = 0; j < 4; ++j) {
                    double s = 0.0;
                    for (int k = 0; k < 4; ++k) s += M[i][k] * M[k][j];
                    T[i][j] = s;
                    double a = fabs(s); if (a > mx) mx = a;
                }
            if (mx < 1e-300) break;
            double inv = 1.0 / mx;
            for (int i = 0; i < 4; ++i) for (int j = 0; j < 4; ++j) M[i][j] = T[i][j] * inv;
        }
        int jb = 0; double bn = -1.0;
        for (int j = 0; j < 4; ++j) {
            double nn = 0.0;
            for (int i = 0; i < 4; ++i) nn += M[i][j] * M[i][j];
            if (nn > bn) { bn = nn; jb = j; }
        }
        double v[4]; for (int i = 0; i < 4; ++i) v[i] = M[i][jb];
        double Av[4];
        for (int i = 0; i < 4; ++i) {
            double s = 0.0;
            for (int j = 0; j < 4; ++j) s += A[i][j] * v[j];
            Av[i] = s;
        }
        double vv = 0.0, vav = 0.0;
        for (int i = 0; i < 4; ++i) { vv += v[i] * v[i]; vav += v[i] * Av[i]; }
        float lamf = (float)((vv > 0.0) ? (vav / vv) : 0.0);
        float tau = expf(fmaxf(taus_p[f], 0.0f));
        float qsv = SCALE_C / tau;
        for (int l = 0; l < 4; ++l)
            for (int g = 0; g < 4; ++g)
                wsf[QEQN_F + f * 32 + l * 4 + g] = qsv * Qm[l][g] / lamf;
        for (int g = 0; g < 4; ++g)
            for (int l = 0; l < 4; ++l)
                wsf[QEQN_F + f * 32 + 16 + g * 4 + l] = SCALE_C * Qm[g][l];
    }
    if (tid >= 48 && tid < 50) {
        const int b = tid - 48;
        float lamb_e = expf(lamb[0]);
        float sg = sigma[b];
        float t = sg * 20.0f - 2.0f;
        float h1[F_], h2[F_];
        for (int j = 0; j < F_; ++j) h1[j] = fmaxf(t * mw1[j] + mb1[j], 0.0f);
        for (int j = 0; j < F_; ++j) {
            float s = mb2[j];
            for (int k = 0; k < F_; ++k) s += h1[k] * mw2[k * F_ + j];
            h2[j] = fmaxf(s, 0.0f);
        }
        for (int j = 0; j < F_; ++j) {
            float s = mb3[j];
            for (int k = 0; k < F_; ++k) s += h2[k] * mw3[k * F_ + j];
            float sc = fmaxf(s * 0.05f + sg, 0.0f) + 1e-9f;
            wsf[SINV_F + b * F_ + j] = 1.0f / sc;
            wsf[SLAM_F + b * F_ + j] = lamb_e * sc;
        }
    }
    if (tid == 50) {
        float lamb_e = expf(lamb[0]);
        float eps_e = expf(eps_om[0]);
        wsf[MISC_F + 0] = eps_e;
        wsf[MISC_F + 1] = 1.0f / (1.0f + lamb_e * (1.0f + eps_e));
    }
}

// ---------------- setup: fragment packing (grid-parallel; AFTER setup_math) ----------------
__global__ void setup_pack(const float* __restrict__ Wf, float* __restrict__ wsf)
{
    unsigned short* wsu = (unsigned short*)wsf;
    const int gtid = blockIdx.x * TPB + threadIdx.x;
    for (int i = gtid; i < 98304; i += gridDim.x * TPB) {
        if (i < 49152) {
            // pass-1 A frags: 24 mtiles. even = Wf (v-rows), odd = Qeq.Wf (y-rows)
            int j = i & 7, lane = (i >> 3) & 63;
            int t = i >> 9;                // 0..95
            int ks = t & 3, mtile = t >> 2;
            int rt = lane & 15, qq = lane >> 4;
            int c = ks * 32 + qq * 8 + j;
            int ft = mtile >> 1;
            int f = ft * 4 + (rt >> 2);
            int gl = rt & 3;
            float w;
            if ((mtile & 1) == 0) {
                w = Wf[(gl * F_ + f) * C_ + c];
            } else {
                w = 0.f;
                for (int g = 0; g < 4; ++g)
                    w += wsf[QEQN_F + f * 32 + gl * 4 + g] * Wf[(g * F_ + f) * C_ + c];
            }
            _Float16 hv = (_Float16)w;
            wsu[P1_U + ((mtile * 4 + ks) * 64 + lane) * 8 + j] = *(unsigned short*)&hv;
        } else {
            // pass-2 A frags: K=384. ks<6: Wf^T (u part); ks>=6: -(SCALE*Qm)^T fold (m2 part)
            int ii = i - 49152;
            int j = ii & 7, lane = (ii >> 3) & 63;
            int t = ii >> 9;               // 0..95
            int ks = t % 12, cmt = t / 12;
            int m = lane & 15, qq = lane >> 4;
            int cch = cmt * 16 + m;
            int r = ks * 32 + qq * 8 + j;  // 0..383
            float w;
            if (ks < 6) {
                int f = r >> 2, g = r & 3;
                w = Wf[(g * F_ + f) * C_ + cch];
            } else {
                int rp = r - 192;
                int f = rp >> 2, l = rp & 3;
                w = 0.f;
                for (int g = 0; g < 4; ++g)
                    w += wsf[QEQN_F + f * 32 + 16 + l * 4 + g] * Wf[(g * F_ + f) * C_ + cch];
                w = -w;
            }
            _Float16 hv = (_Float16)w;
            wsu[P2_U + ((cmt * 12 + ks) * 64 + lane) * 8 + j] = *(unsigned short*)&hv;
        }
    }
}

// Euclidean projection of a 4-vector onto the unit l1 ball (per lane, in regs)
__device__ __forceinline__ void proj4(const float v[4], float o[4]) {
    float a0 = fabsf(v[0]), a1 = fabsf(v[1]), a2 = fabsf(v[2]), a3 = fabsf(v[3]);
    float sum = a0 + a1 + a2 + a3;
    float t0 = fmaxf(a0, a1), u0 = fminf(a0, a1);
    float t1 = fmaxf(a2, a3), u1 = fminf(a2, a3);
    float s0 = fmaxf(t0, t1), m0 = fminf(t0, t1);
    float m1 = fmaxf(u0, u1), s3 = fminf(u0, u1);
    float s1 = fmaxf(m1, m0), s2 = fminf(m1, m0);
    float c2 = s0 + s1, c3 = c2 + s2, c4 = c3 + s3;
    float th = s0 - 1.0f, rs = 1.0f;
    if (s1 * 2.0f > c2 - 1.0f) { th = c2 - 1.0f; rs = 0.5f; }
    if (s2 * 3.0f > c3 - 1.0f) { th = c3 - 1.0f; rs = (1.0f / 3.0f); }
    if (s3 * 4.0f > c4 - 1.0f) { th = c4 - 1.0f; rs = 0.25f; }
    float theta = fmaxf(th * rs, 0.0f);
    bool inside = (sum <= 1.0f);
#pragma unroll
    for (int g = 0; g < 4; ++g) {
        float ag = fabsf(v[g]);
        float pg = copysignf(fmaxf(ag - theta, 0.0f), v[g]);
        o[g] = inside ? v[g] : pg;
    }
}

// ---------------- main: 64-pixel tile, 8 waves/block, 512 blocks ----------------
// Pass-1 r6c2: wave = (ftg = wv>>1 -> 3 ft-pairs, nph = wv&1 -> 2 np tiles).
//   12 MFMAs per kstep hide the 6 global A-loads; LDS B traffic /3 vs r2c2.
// Pass-2 r1c4: wave = cmt = wv, all 4 np (A-minimal). First 4 A-frags prefetched
//   before the mid barrier so their L2 latency hides under activation VALU.
// x is carried in sXF (f16); x_noisy anchor in 16 f32 regs.
__global__ __launch_bounds__(MTPB, 4) void mfoe_main(
    const float* __restrict__ xnoisy,
    const float* __restrict__ wsf,
    float* __restrict__ out,
    const int* __restrict__ n_iter_p)
{
    __shared__ __align__(16) _Float16 sXF[8192];    // [np(4)][ks(4)][lane(64)][j(8)]
    __shared__ __align__(16) _Float16 sACT[24576];  // [np(4)][ks(12)][lane(64)][j(8)]

    const int tid = threadIdx.x;
    const int lane = tid & 63;
    const int wv = __builtin_amdgcn_readfirstlane(tid >> 6);   // SGPR wave id, 0..7
    const int n = lane & 15;
    const int q = lane >> 4;
    const int blk = blockIdx.x;
    const int b = blk >> 8;                 // 256 blocks per image
    const int pix0 = (blk & 255) << 6;      // 64 pixels per block

    const float* __restrict__ xin = xnoisy + b * (C_ * HW) + pix0;
    float* __restrict__ oimg = out + b * (C_ * HW) + pix0;
    const unsigned short* __restrict__ wsu = (const unsigned short*)wsf;
    const int niter = *n_iter_p;

    if (niter == 0) {
        for (int i = tid; i < C_ * 64; i += MTPB) {
            int p = i & 63, c = i >> 6;
            oimg[c * HW + p] = xin[c * HW + p];
        }
        return;
    }

    // stage x -> LDS f16 in fragment order
    for (int i = tid; i < C_ * 64; i += MTPB) {
        int p = i & 63, c = i >> 6;
        int idx = (((p >> 4) * 4 + (c >> 5)) * 64 + ((c >> 3) & 3) * 16 + (p & 15)) * 8 + (c & 7);
        sXF[idx] = (_Float16)xin[c * HW + p];
    }

    const int ftg = wv >> 1;    // 0..3: pass-1 ft group (3 ft-pairs)
    const int nph = wv & 1;     // pass-1 np-pair

    // per-lane activation constants (iteration-invariant): f = (ftg*3+t)*4 + q
    float invsr[3], slamr[3];
#pragma unroll
    for (int t = 0; t < 3; ++t) {
        int f = (ftg * 3 + t) * 4 + q;
        invsr[t] = wsf[SINV_F + b * F_ + f];
        slamr[t] = wsf[SLAM_F + b * F_ + f];
    }
    // x_noisy anchor in registers (update layout: cmt = wv)
    float xnr[16];
#pragma unroll
    for (int np = 0; np < 4; ++np)
#pragma unroll
        for (int l = 0; l < 4; ++l)
            xnr[np * 4 + l] = xin[(wv * 16 + q * 4 + l) * HW + np * 16 + n];

    const float eps_e = wsf[MISC_F + 0];
    const float invden = wsf[MISC_F + 1];

    const half8* __restrict__ A1 = (const half8*)wsu;              // P1 frags
    const half8* __restrict__ A2 = (const half8*)(wsu + P2_U);     // P2 frags
    const half8* __restrict__ sXF8 = (const half8*)sXF;
    const half8* __restrict__ sACT8 = (const half8*)sACT;

    for (int it = 0; it < niter; ++it) {
        __syncthreads();   // x ready
        // ---- pass 1: r6c2 — 3 ft-pairs (v,y) x 2 np per wave
        floatx4 av[3][2], ay[3][2];
#pragma unroll
        for (int t = 0; t < 3; ++t)
#pragma unroll
            for (int h = 0; h < 2; ++h) {
                av[t][h] = (floatx4){0.f, 0.f, 0.f, 0.f};
                ay[t][h] = (floatx4){0.f, 0.f, 0.f, 0.f};
            }
#pragma unroll
        for (int ks = 0; ks < 4; ++ks) {
            half8 aV0 = A1[(((ftg * 3 + 0) * 2 + 0) * 4 + ks) * 64 + lane];
            half8 aY0 = A1[(((ftg * 3 + 0) * 2 + 1) * 4 + ks) * 64 + lane];
            half8 aV1 = A1[(((ftg * 3 + 1) * 2 + 0) * 4 + ks) * 64 + lane];
            half8 aY1 = A1[(((ftg * 3 + 1) * 2 + 1) * 4 + ks) * 64 + lane];
            half8 aV2 = A1[(((ftg * 3 + 2) * 2 + 0) * 4 + ks) * 64 + lane];
            half8 aY2 = A1[(((ftg * 3 + 2) * 2 + 1) * 4 + ks) * 64 + lane];
            half8 b0 = sXF8[((nph * 2 + 0) * 4 + ks) * 64 + lane];
            half8 b1 = sXF8[((nph * 2 + 1) * 4 + ks) * 64 + lane];
            av[0][0] = __builtin_amdgcn_mfma_f32_16x16x32_f16(aV0, b0, av[0][0], 0, 0, 0);
            ay[0][0] = __builtin_amdgcn_mfma_f32_16x16x32_f16(aY0, b0, ay[0][0], 0, 0, 0);
            av[0][1] = __builtin_amdgcn_mfma_f32_16x16x32_f16(aV0, b1, av[0][1], 0, 0, 0);
            ay[0][1] = __builtin_amdgcn_mfma_f32_16x16x32_f16(aY0, b1, ay[0][1], 0, 0, 0);
            av[1][0] = __builtin_amdgcn_mfma_f32_16x16x32_f16(aV1, b0, av[1][0], 0, 0, 0);
            ay[1][0] = __builtin_amdgcn_mfma_f32_16x16x32_f16(aY1, b0, ay[1][0], 0, 0, 0);
            av[1][1] = __builtin_amdgcn_mfma_f32_16x16x32_f16(aV1, b1, av[1][1], 0, 0, 0);
            ay[1][1] = __builtin_amdgcn_mfma_f32_16x16x32_f16(aY1, b1, ay[1][1], 0, 0, 0);
            av[2][0] = __builtin_amdgcn_mfma_f32_16x16x32_f16(aV2, b0, av[2][0], 0, 0, 0);
            ay[2][0] = __builtin_amdgcn_mfma_f32_16x16x32_f16(aY2, b0, ay[2][0], 0, 0, 0);
            av[2][1] = __builtin_amdgcn_mfma_f32_16x16x32_f16(aV2, b1, av[2][1], 0, 0, 0);
            ay[2][1] = __builtin_amdgcn_mfma_f32_16x16x32_f16(aY2, b1, ay[2][1], 0, 0, 0);
        }
        // prefetch pass-2 A frags (latency hides under activation VALU below)
        half8 a2[4];
#pragma unroll
        for (int k = 0; k < 4; ++k) a2[k] = A2[(wv * 12 + k) * 64 + lane];
        // ---- activation: 6 (ft,np) cells per wave; lane owns f = (ftg*3+t)*4+q
#pragma unroll
        for (int t = 0; t < 3; ++t) {
            const float invs = invsr[t];
            const float slam = slamr[t];
            const int ft = ftg * 3 + t;
#pragma unroll
            for (int h = 0; h < 2; ++h) {
                const int np = nph * 2 + h;
                float v[4] = {av[t][h][0] * invs, av[t][h][1] * invs,
                              av[t][h][2] * invs, av[t][h][3] * invs};
                float y[4] = {ay[t][h][0] * invs, ay[t][h][1] * invs,
                              ay[t][h][2] * invs, ay[t][h][3] * invs};
                float pv[4]; proj4(v, pv);
                float py[4]; proj4(y, py);
                half4 au, am;
#pragma unroll
                for (int g = 0; g < 4; ++g) {
                    au[g] = (_Float16)(fmaf(eps_e, v[g], pv[g]) * slam);
                    am[g] = (_Float16)(fmaf(eps_e, y[g], py[g]) * slam);
                }
                int aw = ((np * 12 + (ft >> 1)) * 64 + ((ft & 1) * 2 + (q >> 1)) * 16 + n) * 8 + (q & 1) * 4;
                *(half4*)&sACT[aw] = au;
                *(half4*)&sACT[aw + 3072] = am;
            }
        }
        __syncthreads();   // act ready; all pass-1 x reads done
        // ---- pass 2: cmt = wv, 4 np, K=384
        floatx4 acc2[4];
#pragma unroll
        for (int np = 0; np < 4; ++np) acc2[np] = (floatx4){0.f, 0.f, 0.f, 0.f};
#pragma unroll
        for (int ks = 0; ks < 12; ++ks) {
            half8 aF = (ks < 4) ? a2[ks] : A2[(wv * 12 + ks) * 64 + lane];
            half8 bA0 = sACT8[(0 * 12 + ks) * 64 + lane];
            half8 bA1 = sACT8[(1 * 12 + ks) * 64 + lane];
            half8 bA2 = sACT8[(2 * 12 + ks) * 64 + lane];
            half8 bA3 = sACT8[(3 * 12 + ks) * 64 + lane];
            acc2[0] = __builtin_amdgcn_mfma_f32_16x16x32_f16(aF, bA0, acc2[0], 0, 0, 0);
            acc2[1] = __builtin_amdgcn_mfma_f32_16x16x32_f16(aF, bA1, acc2[1], 0, 0, 0);
            acc2[2] = __builtin_amdgcn_mfma_f32_16x16x32_f16(aF, bA2, acc2[2], 0, 0, 0);
            acc2[3] = __builtin_amdgcn_mfma_f32_16x16x32_f16(aF, bA3, acc2[3], 0, 0, 0);
        }
        // ---- update: thread owns (cmt=wv, q, np 0..3); x carried in sXF (f16)
        const bool last = (it == niter - 1);
#pragma unroll
        for (int np = 0; np < 4; ++np) {
            int p = np * 16 + n;
            int xu = ((np * 4 + (wv >> 1)) * 64 + ((wv & 1) * 2 + (q >> 1)) * 16 + n) * 8 + (q & 1) * 4;
            half4 xo4 = *(const half4*)&sXF[xu];
            half4 nx4;
#pragma unroll
            for (int l = 0; l < 4; ++l) {
                float xo = (float)xo4[l];
                float nx = xo - ((xo - xnr[np * 4 + l]) + acc2[np][l]) * invden;
                nx4[l] = (_Float16)nx;
                if (last) oimg[(wv * 16 + q * 4 + l) * HW + p] = nx;
            }
            *(half4*)&sXF[xu] = nx4;
        }
    }
}

extern "C" void kernel_launch(void* const* d_in, const int* in_sizes, int n_in,
                              void* d_out, int out_size, void* d_ws, size_t ws_size,
                              hipStream_t stream) {
    const float* x_noisy = (const float*)d_in[0];
    const float* sigma   = (const float*)d_in[1];
    const float* Qp      = (const float*)d_in[2];
    const float* taus_p  = (const float*)d_in[3];
    const float* lamb    = (const float*)d_in[4];
    const float* eps_om  = (const float*)d_in[5];
    const float* mw1     = (const float*)d_in[6];
    const float* mb1     = (const float*)d_in[7];
    const float* mw2     = (const float*)d_in[8];
    const float* mb2     = (const float*)d_in[9];
    const float* mw3     = (const float*)d_in[10];
    const float* mb3     = (const float*)d_in[11];
    const float* Wf      = (const float*)d_in[12];
    const int*   n_iter  = (const int*)d_in[13];
    float* out = (float*)d_out;
    float* ws  = (float*)d_ws;

    hipLaunchKernelGGL(setup_math, dim3(1), dim3(64), 0, stream,
                       sigma, Qp, taus_p, lamb, eps_om,
                       mw1, mb1, mw2, mb2, mw3, mb3, ws);
    hipLaunchKernelGGL(setup_pack, dim3(192), dim3(TPB), 0, stream, Wf, ws);
    hipLaunchKernelGGL(mfoe_main, dim3(512), dim3(MTPB), 0, stream,
                       x_noisy, ws, out, n_iter);
}

// Round 6
// 274.748 us; speedup vs baseline: 1.7118x; 1.7118x over previous
//
#include <hip/hip_runtime.h>
#include <math.h>

#define F_ 48
#define C_ 128
#define HW 16384
#define SCALE_C 0.999f
#define TPB 256      // setup kernels
#define MTPB 512     // main kernel: 8 waves/block

typedef __attribute__((ext_vector_type(4))) float floatx4;
typedef __attribute__((ext_vector_type(8))) _Float16 half8;
typedef __attribute__((ext_vector_type(4))) _Float16 half4;

// ---- ws layout ----
// ushort region:
//   P1 frags (f16): [mtile(24)][ks(4)][lane(64)][j(8)] = 49152 ushorts
//     even mtile = Wf rows (v), odd mtile = (Qeq.Wf) rows (y), paired per f-group
//   P2 frags (f16): [cmt(8)][ks(12)][lane(64)][j(8)] = 49152 ushorts at 49152
//     ks 0..5 = Wf^T (u part), ks 6..11 = -(SCALE*Qm)^T-folded Wf (m2 part)
// float region at float offset 49152 (byte 196608):
#define P1_U 0
#define P2_U 49152
#define QEQN_F 49152              // [48][32]: [0..15]=Qeq[l][g], [16..31]=SCALE*Qm[a][b]
#define MISC_F (QEQN_F + 1536)    // eps_e, invden
#define SINV_F (MISC_F + 2)       // [2][48] 1/scaling
#define SLAM_F (SINV_F + 96)      // [2][48] lamb_e*scaling

// ---------------- setup: math (1 block, tiny) ----------------
__global__ void setup_math(const float* __restrict__ sigma,
                           const float* __restrict__ Qp,
                           const float* __restrict__ taus_p,
                           const float* __restrict__ lamb,
                           const float* __restrict__ eps_om,
                           const float* __restrict__ mw1, const float* __restrict__ mb1,
                           const float* __restrict__ mw2, const float* __restrict__ mb2,
                           const float* __restrict__ mw3, const float* __restrict__ mb3,
                           float* __restrict__ wsf)
{
    const int tid = threadIdx.x;
    if (tid < F_) {
        const int f = tid;
        float Qm[4][4];
        for (int g = 0; g < 4; ++g) {
            float s = 0.f;
            for (int l = 0; l < 4; ++l) s += fabsf(Qp[f * 16 + g * 4 + l]);
            float d = fmaxf(s, 1.0f);
            for (int l = 0; l < 4; ++l) Qm[g][l] = Qp[f * 16 + g * 4 + l] / d;
        }
        double A[4][4];
        for (int i = 0; i < 4; ++i)
            for (int j = 0; j < 4; ++j) {
                double s = 0.0;
                for (int g = 0; g < 4; ++g) s += (double)Qm[g][i] * (double)Qm[g][j];
                A[i][j] = s;
            }
        double M[4][4];
        for (int i = 0; i < 4; ++i) for (int j = 0; j < 4; ++j) M[i][j] = A[i][j];
        for (int it = 0; it < 30; ++it) {
            double T[4][4]; double mx = 0.0;
            for (int i = 0; i < 4; ++i)
                for (int j = 0; j < 4; ++j) {
                    double s = 0.0;
                    for (int k = 0; k < 4; ++k) s += M[i][k] * M[k][j];
                    T[i][j] = s;
                    double a = fabs(s); if (a > mx) mx = a;
                }
            if (mx < 1e-300) break;
            double inv = 1.0 / mx;
            for (int i = 0; i < 4; ++i) for (int j = 0; j < 4; ++j) M[i][j] = T[i][j] * inv;
        }
        int jb = 0; double bn = -1.0;
        for (int j = 0; j < 4; ++j) {
            double nn = 0.0;
            for (int i = 0; i < 4; ++i) nn += M[i][j] * M[i][j];
            if (nn > bn) { bn = nn; jb = j; }
        }
        double v[4]; for (int i = 0; i < 4; ++i) v[i] = M[i][jb];
        double Av[4];
        for (int i = 0; i < 4; ++i) {
            double s = 0.0;
            for (int j = 0; j < 4; ++j) s += A[i][j] * v[j];
            Av[i] = s;
        }
        double vv = 0.0, vav = 0.0;
        for (int i = 0; i < 4; ++i) { vv += v[i] * v[i]; vav += v[i] * Av[i]; }
        float lamf = (float)((vv > 0.0) ? (vav / vv) : 0.0);
        float tau = expf(fmaxf(taus_p[f], 0.0f));
        float qsv = SCALE_C / tau;
        for (int l = 0; l < 4; ++l)
            for (int g = 0; g < 4; ++g)
                wsf[QEQN_F + f * 32 + l * 4 + g] = qsv * Qm[l][g] / lamf;
        for (int g = 0; g < 4; ++g)
            for (int l = 0; l < 4; ++l)
                wsf[QEQN_F + f * 32 + 16 + g * 4 + l] = SCALE_C * Qm[g][l];
    }
    if (tid >= 48 && tid < 50) {
        const int b = tid - 48;
        float lamb_e = expf(lamb[0]);
        float sg = sigma[b];
        float t = sg * 20.0f - 2.0f;
        float h1[F_], h2[F_];
        for (int j = 0; j < F_; ++j) h1[j] = fmaxf(t * mw1[j] + mb1[j], 0.0f);
        for (int j = 0; j < F_; ++j) {
            float s = mb2[j];
            for (int k = 0; k < F_; ++k) s += h1[k] * mw2[k * F_ + j];
            h2[j] = fmaxf(s, 0.0f);
        }
        for (int j = 0; j < F_; ++j) {
            float s = mb3[j];
            for (int k = 0; k < F_; ++k) s += h2[k] * mw3[k * F_ + j];
            float sc = fmaxf(s * 0.05f + sg, 0.0f) + 1e-9f;
            wsf[SINV_F + b * F_ + j] = 1.0f / sc;
            wsf[SLAM_F + b * F_ + j] = lamb_e * sc;
        }
    }
    if (tid == 50) {
        float lamb_e = expf(lamb[0]);
        float eps_e = expf(eps_om[0]);
        wsf[MISC_F + 0] = eps_e;
        wsf[MISC_F + 1] = 1.0f / (1.0f + lamb_e * (1.0f + eps_e));
    }
}

// ---------------- setup: fragment packing (grid-parallel; AFTER setup_math) ----------------
__global__ void setup_pack(const float* __restrict__ Wf, float* __restrict__ wsf)
{
    unsigned short* wsu = (unsigned short*)wsf;
    const int gtid = blockIdx.x * TPB + threadIdx.x;
    for (int i = gtid; i < 98304; i += gridDim.x * TPB) {
        if (i < 49152) {
            // pass-1 A frags: 24 mtiles. even = Wf (v-rows), odd = Qeq.Wf (y-rows)
            int j = i & 7, lane = (i >> 3) & 63;
            int t = i >> 9;                // 0..95
            int ks = t & 3, mtile = t >> 2;
            int rt = lane & 15, qq = lane >> 4;
            int c = ks * 32 + qq * 8 + j;
            int ft = mtile >> 1;
            int f = ft * 4 + (rt >> 2);
            int gl = rt & 3;
            float w;
            if ((mtile & 1) == 0) {
                w = Wf[(gl * F_ + f) * C_ + c];
            } else {
                w = 0.f;
                for (int g = 0; g < 4; ++g)
                    w += wsf[QEQN_F + f * 32 + gl * 4 + g] * Wf[(g * F_ + f) * C_ + c];
            }
            _Float16 hv = (_Float16)w;
            wsu[P1_U + ((mtile * 4 + ks) * 64 + lane) * 8 + j] = *(unsigned short*)&hv;
        } else {
            // pass-2 A frags: K=384. ks<6: Wf^T (u part); ks>=6: -(SCALE*Qm)^T fold (m2 part)
            int ii = i - 49152;
            int j = ii & 7, lane = (ii >> 3) & 63;
            int t = ii >> 9;               // 0..95
            int ks = t % 12, cmt = t / 12;
            int m = lane & 15, qq = lane >> 4;
            int cch = cmt * 16 + m;
            int r = ks * 32 + qq * 8 + j;  // 0..383
            float w;
            if (ks < 6) {
                int f = r >> 2, g = r & 3;
                w = Wf[(g * F_ + f) * C_ + cch];
            } else {
                int rp = r - 192;
                int f = rp >> 2, l = rp & 3;
                w = 0.f;
                for (int g = 0; g < 4; ++g)
                    w += wsf[QEQN_F + f * 32 + 16 + l * 4 + g] * Wf[(g * F_ + f) * C_ + cch];
                w = -w;
            }
            _Float16 hv = (_Float16)w;
            wsu[P2_U + ((cmt * 12 + ks) * 64 + lane) * 8 + j] = *(unsigned short*)&hv;
        }
    }
}

// Euclidean projection of a 4-vector onto the unit l1 ball (per lane, in regs)
__device__ __forceinline__ void proj4(const float v[4], float o[4]) {
    float a0 = fabsf(v[0]), a1 = fabsf(v[1]), a2 = fabsf(v[2]), a3 = fabsf(v[3]);
    float sum = a0 + a1 + a2 + a3;
    float t0 = fmaxf(a0, a1), u0 = fminf(a0, a1);
    float t1 = fmaxf(a2, a3), u1 = fminf(a2, a3);
    float s0 = fmaxf(t0, t1), m0 = fminf(t0, t1);
    float m1 = fmaxf(u0, u1), s3 = fminf(u0, u1);
    float s1 = fmaxf(m1, m0), s2 = fminf(m1, m0);
    float c2 = s0 + s1, c3 = c2 + s2, c4 = c3 + s3;
    float th = s0 - 1.0f, rs = 1.0f;
    if (s1 * 2.0f > c2 - 1.0f) { th = c2 - 1.0f; rs = 0.5f; }
    if (s2 * 3.0f > c3 - 1.0f) { th = c3 - 1.0f; rs = (1.0f / 3.0f); }
    if (s3 * 4.0f > c4 - 1.0f) { th = c4 - 1.0f; rs = 0.25f; }
    float theta = fmaxf(th * rs, 0.0f);
    bool inside = (sum <= 1.0f);
#pragma unroll
    for (int g = 0; g < 4; ++g) {
        float ag = fabsf(v[g]);
        float pg = copysignf(fmaxf(ag - theta, 0.0f), v[g]);
        o[g] = inside ? v[g] : pg;
    }
}

// ---------------- main: 64-pixel tile, 8 waves/block, 512 blocks ----------------
// __launch_bounds__(512,2): VGPR cap 128 (the (512,4) bound capped at 64 and
// caused R5's scratch-spill catastrophe — hbm_bytes 1e9). LDS 64KB -> 2 blk/CU,
// all 512 blocks co-resident.
// Pass-1: 3 unrolled jobs of (1 ft-pair, 2 np): 16 acc VGPRs per job; compiler
// overlaps job t+1's 8 global A-loads under job t's activation VALU.
// Pass-2: cmt = wv, 4 np, K=384; first 4 A-frags prefetched before mid barrier.
__global__ __launch_bounds__(MTPB, 2) void mfoe_main(
    const float* __restrict__ xnoisy,
    const float* __restrict__ wsf,
    float* __restrict__ out,
    const int* __restrict__ n_iter_p)
{
    __shared__ __align__(16) _Float16 sXF[8192];    // [np(4)][ks(4)][lane(64)][j(8)]
    __shared__ __align__(16) _Float16 sACT[24576];  // [np(4)][ks(12)][lane(64)][j(8)]

    const int tid = threadIdx.x;
    const int lane = tid & 63;
    const int wv = __builtin_amdgcn_readfirstlane(tid >> 6);   // SGPR wave id, 0..7
    const int n = lane & 15;
    const int q = lane >> 4;
    const int blk = blockIdx.x;
    const int b = blk >> 8;                 // 256 blocks per image
    const int pix0 = (blk & 255) << 6;      // 64 pixels per block

    const float* __restrict__ xin = xnoisy + b * (C_ * HW) + pix0;
    float* __restrict__ oimg = out + b * (C_ * HW) + pix0;
    const unsigned short* __restrict__ wsu = (const unsigned short*)wsf;
    const int niter = *n_iter_p;

    if (niter == 0) {
        for (int i = tid; i < C_ * 64; i += MTPB) {
            int p = i & 63, c = i >> 6;
            oimg[c * HW + p] = xin[c * HW + p];
        }
        return;
    }

    // stage x -> LDS f16 in fragment order
    for (int i = tid; i < C_ * 64; i += MTPB) {
        int p = i & 63, c = i >> 6;
        int idx = (((p >> 4) * 4 + (c >> 5)) * 64 + ((c >> 3) & 3) * 16 + (p & 15)) * 8 + (c & 7);
        sXF[idx] = (_Float16)xin[c * HW + p];
    }

    // per-lane activation constants (iteration-invariant): job jj -> ft=(wv*3+jj)>>1
    float invsr[3], slamr[3];
#pragma unroll
    for (int jj = 0; jj < 3; ++jj) {
        int f = (((wv * 3 + jj) >> 1) << 2) + q;
        invsr[jj] = wsf[SINV_F + b * F_ + f];
        slamr[jj] = wsf[SLAM_F + b * F_ + f];
    }
    // x_noisy anchor in registers (update layout: cmt = wv)
    float xnr[16];
#pragma unroll
    for (int np = 0; np < 4; ++np)
#pragma unroll
        for (int l = 0; l < 4; ++l)
            xnr[np * 4 + l] = xin[(wv * 16 + q * 4 + l) * HW + np * 16 + n];

    const float eps_e = wsf[MISC_F + 0];
    const float invden = wsf[MISC_F + 1];

    const half8* __restrict__ A1 = (const half8*)wsu;              // P1 frags
    const half8* __restrict__ A2 = (const half8*)(wsu + P2_U);     // P2 frags
    const half8* __restrict__ sXF8 = (const half8*)sXF;
    const half8* __restrict__ sACT8 = (const half8*)sACT;

    for (int it = 0; it < niter; ++it) {
        __syncthreads();   // x ready
        // ---- pass 1: 3 unrolled jobs of (ft, np-pair); 16 MFMA + act each
#pragma unroll
        for (int jj = 0; jj < 3; ++jj) {
            const int grp = wv * 3 + jj;
            const int ft = grp >> 1;
            const int np0 = (grp & 1) * 2;
            floatx4 av0 = (floatx4){0.f, 0.f, 0.f, 0.f};
            floatx4 av1 = (floatx4){0.f, 0.f, 0.f, 0.f};
            floatx4 ay0 = (floatx4){0.f, 0.f, 0.f, 0.f};
            floatx4 ay1 = (floatx4){0.f, 0.f, 0.f, 0.f};
#pragma unroll
            for (int ks = 0; ks < 4; ++ks) {
                half8 aV = A1[((ft * 2 + 0) * 4 + ks) * 64 + lane];
                half8 aY = A1[((ft * 2 + 1) * 4 + ks) * 64 + lane];
                half8 b0 = sXF8[((np0 + 0) * 4 + ks) * 64 + lane];
                half8 b1 = sXF8[((np0 + 1) * 4 + ks) * 64 + lane];
                av0 = __builtin_amdgcn_mfma_f32_16x16x32_f16(aV, b0, av0, 0, 0, 0);
                ay0 = __builtin_amdgcn_mfma_f32_16x16x32_f16(aY, b0, ay0, 0, 0, 0);
                av1 = __builtin_amdgcn_mfma_f32_16x16x32_f16(aV, b1, av1, 0, 0, 0);
                ay1 = __builtin_amdgcn_mfma_f32_16x16x32_f16(aY, b1, ay1, 0, 0, 0);
            }
            // ---- activation: 2 np cells; lane owns f = ft*4+q
            const float invs = invsr[jj];
            const float slam = slamr[jj];
#pragma unroll
            for (int h = 0; h < 2; ++h) {
                const int np = np0 + h;
                floatx4 accv = h ? av1 : av0;
                floatx4 accy = h ? ay1 : ay0;
                float v[4] = {accv[0] * invs, accv[1] * invs, accv[2] * invs, accv[3] * invs};
                float y[4] = {accy[0] * invs, accy[1] * invs, accy[2] * invs, accy[3] * invs};
                float pv[4]; proj4(v, pv);
                float py[4]; proj4(y, py);
                half4 au, am;
#pragma unroll
                for (int g = 0; g < 4; ++g) {
                    au[g] = (_Float16)(fmaf(eps_e, v[g], pv[g]) * slam);
                    am[g] = (_Float16)(fmaf(eps_e, y[g], py[g]) * slam);
                }
                int aw = ((np * 12 + (ft >> 1)) * 64 + ((ft & 1) * 2 + (q >> 1)) * 16 + n) * 8 + (q & 1) * 4;
                *(half4*)&sACT[aw] = au;
                *(half4*)&sACT[aw + 3072] = am;
            }
        }
        // prefetch pass-2 A frags (L2 latency hides under barrier drain)
        half8 a2[4];
#pragma unroll
        for (int k = 0; k < 4; ++k) a2[k] = A2[(wv * 12 + k) * 64 + lane];
        __syncthreads();   // act ready; all pass-1 x reads done
        // ---- pass 2: cmt = wv, 4 np, K=384
        floatx4 acc2[4];
#pragma unroll
        for (int np = 0; np < 4; ++np) acc2[np] = (floatx4){0.f, 0.f, 0.f, 0.f};
#pragma unroll
        for (int ks = 0; ks < 12; ++ks) {
            half8 aF = (ks < 4) ? a2[ks] : A2[(wv * 12 + ks) * 64 + lane];
            half8 bA0 = sACT8[(0 * 12 + ks) * 64 + lane];
            half8 bA1 = sACT8[(1 * 12 + ks) * 64 + lane];
            half8 bA2 = sACT8[(2 * 12 + ks) * 64 + lane];
            half8 bA3 = sACT8[(3 * 12 + ks) * 64 + lane];
            acc2[0] = __builtin_amdgcn_mfma_f32_16x16x32_f16(aF, bA0, acc2[0], 0, 0, 0);
            acc2[1] = __builtin_amdgcn_mfma_f32_16x16x32_f16(aF, bA1, acc2[1], 0, 0, 0);
            acc2[2] = __builtin_amdgcn_mfma_f32_16x16x32_f16(aF, bA2, acc2[2], 0, 0, 0);
            acc2[3] = __builtin_amdgcn_mfma_f32_16x16x32_f16(aF, bA3, acc2[3], 0, 0, 0);
        }
        // ---- update: thread owns (cmt=wv, q, np 0..3); x carried in sXF (f16)
        const bool last = (it == niter - 1);
#pragma unroll
        for (int np = 0; np < 4; ++np) {
            int p = np * 16 + n;
            int xu = ((np * 4 + (wv >> 1)) * 64 + ((wv & 1) * 2 + (q >> 1)) * 16 + n) * 8 + (q & 1) * 4;
            half4 xo4 = *(const half4*)&sXF[xu];
            half4 nx4;
#pragma unroll
            for (int l = 0; l < 4; ++l) {
                float xo = (float)xo4[l];
                float nx = xo - ((xo - xnr[np * 4 + l]) + acc2[np][l]) * invden;
                nx4[l] = (_Float16)nx;
                if (last) oimg[(wv * 16 + q * 4 + l) * HW + p] = nx;
            }
            *(half4*)&sXF[xu] = nx4;
        }
    }
}

extern "C" void kernel_launch(void* const* d_in, const int* in_sizes, int n_in,
                              void* d_out, int out_size, void* d_ws, size_t ws_size,
                              hipStream_t stream) {
    const float* x_noisy = (const float*)d_in[0];
    const float* sigma   = (const float*)d_in[1];
    const float* Qp      = (const float*)d_in[2];
    const float* taus_p  = (const float*)d_in[3];
    const float* lamb    = (const float*)d_in[4];
    const float* eps_om  = (const float*)d_in[5];
    const float* mw1     = (const float*)d_in[6];
    const float* mb1     = (const float*)d_in[7];
    const float* mw2     = (const float*)d_in[8];
    const float* mb2     = (const float*)d_in[9];
    const float* mw3     = (const float*)d_in[10];
    const float* mb3     = (const float*)d_in[11];
    const float* Wf      = (const float*)d_in[12];
    const int*   n_iter  = (const int*)d_in[13];
    float* out = (float*)d_out;
    float* ws  = (float*)d_ws;

    hipLaunchKernelGGL(setup_math, dim3(1), dim3(64), 0, stream,
                       sigma, Qp, taus_p, lamb, eps_om,
                       mw1, mb1, mw2, mb2, mw3, mb3, ws);
    hipLaunchKernelGGL(setup_pack, dim3(192), dim3(TPB), 0, stream, Wf, ws);
    hipLaunchKernelGGL(mfoe_main, dim3(512), dim3(MTPB), 0, stream,
                       x_noisy, ws, out, n_iter);
}

// Round 8
// 273.640 us; speedup vs baseline: 1.7188x; 1.0040x over previous
//
#include <hip/hip_runtime.h>
#include <math.h>

#define F_ 48
#define C_ 128
#define HW 16384
#define SCALE_C 0.999f
#define TPB 256      // setup kernels
#define MTPB 512     // main kernel: 8 waves/block

typedef __attribute__((ext_vector_type(4))) float floatx4;
typedef __attribute__((ext_vector_type(8))) _Float16 half8;
typedef __attribute__((ext_vector_type(4))) _Float16 half4;

// ---- ws layout ----
// ushort region:
//   P1 frags (f16): [mtile(24)][ks(4)][lane(64)][j(8)] = 49152 ushorts
//     even mtile = Wf rows (v), odd mtile = (Qeq.Wf) rows (y), paired per f-group
//   P2 frags (f16): [cmt(8)][ks(6)][lane(64)][j(8)] = 24576 ushorts at 49152
//     (Wf^T only; gcc matvec done in VALU)
// float region at float offset 36864 (byte 147456):
#define P1_U 0
#define P2_U 49152
#define QEQN_F 36864              // [48][32]: [0..15]=Qeq[l][g], [16..31]=SCALE*Qm[g][l]
#define MISC_F (QEQN_F + 1536)    // eps_e, invden
#define SINV_F (MISC_F + 2)       // [2][48] 1/scaling
#define SLAM_F (SINV_F + 96)      // [2][48] lamb_e*scaling

// ---------------- setup: math (1 block, tiny) ----------------
__global__ void setup_math(const float* __restrict__ sigma,
                           const float* __restrict__ Qp,
                           const float* __restrict__ taus_p,
                           const float* __restrict__ lamb,
                           const float* __restrict__ eps_om,
                           const float* __restrict__ mw1, const float* __restrict__ mb1,
                           const float* __restrict__ mw2, const float* __restrict__ mb2,
                           const float* __restrict__ mw3, const float* __restrict__ mb3,
                           float* __restrict__ wsf)
{
    const int tid = threadIdx.x;
    if (tid < F_) {
        const int f = tid;
        float Qm[4][4];
        for (int g = 0; g < 4; ++g) {
            float s = 0.f;
            for (int l = 0; l < 4; ++l) s += fabsf(Qp[f * 16 + g * 4 + l]);
            float d = fmaxf(s, 1.0f);
            for (int l = 0; l < 4; ++l) Qm[g][l] = Qp[f * 16 + g * 4 + l] / d;
        }
        double A[4][4];
        for (int i = 0; i < 4; ++i)
            for (int j = 0; j < 4; ++j) {
                double s = 0.0;
                for (int g = 0; g < 4; ++g) s += (double)Qm[g][i] * (double)Qm[g][j];
                A[i][j] = s;
            }
        double M[4][4];
        for (int i = 0; i < 4; ++i) for (int j = 0; j < 4; ++j) M[i][j] = A[i][j];
        for (int it = 0; it < 30; ++it) {
            double T[4][4]; double mx = 0.0;
            for (int i = 0; i < 4; ++i)
                for (int j = 0; j < 4; ++j) {
                    double s = 0.0;
                    for (int k = 0; k < 4; ++k) s += M[i][k] * M[k][j];
                    T[i][j] = s;
                    double a = fabs(s); if (a > mx) mx = a;
                }
            if (mx < 1e-300) break;
            double inv = 1.0 / mx;
            for (int i = 0; i < 4; ++i) for (int j = 0; j < 4; ++j) M[i][j] = T[i][j] * inv;
        }
        int jb = 0; double bn = -1.0;
        for (int j = 0; j < 4; ++j) {
            double nn = 0.0;
            for (int i = 0; i < 4; ++i) nn += M[i][j] * M[i][j];
            if (nn > bn) { bn = nn; jb = j; }
        }
        double v[4]; for (int i = 0; i < 4; ++i) v[i] = M[i][jb];
        double Av[4];
        for (int i = 0; i < 4; ++i) {
            double s = 0.0;
            for (int j = 0; j < 4; ++j) s += A[i][j] * v[j];
            Av[i] = s;
        }
        double vv = 0.0, vav = 0.0;
        for (int i = 0; i < 4; ++i) { vv += v[i] * v[i]; vav += v[i] * Av[i]; }
        float lamf = (float)((vv > 0.0) ? (vav / vv) : 0.0);
        float tau = expf(fmaxf(taus_p[f], 0.0f));
        float qsv = SCALE_C / tau;
        for (int l = 0; l < 4; ++l)
            for (int g = 0; g < 4; ++g)
                wsf[QEQN_F + f * 32 + l * 4 + g] = qsv * Qm[l][g] / lamf;
        for (int g = 0; g < 4; ++g)
            for (int l = 0; l < 4; ++l)
                wsf[QEQN_F + f * 32 + 16 + g * 4 + l] = SCALE_C * Qm[g][l];
    }
    if (tid >= 48 && tid < 50) {
        const int b = tid - 48;
        float lamb_e = expf(lamb[0]);
        float sg = sigma[b];
        float t = sg * 20.0f - 2.0f;
        float h1[F_], h2[F_];
        for (int j = 0; j < F_; ++j) h1[j] = fmaxf(t * mw1[j] + mb1[j], 0.0f);
        for (int j = 0; j < F_; ++j) {
            float s = mb2[j];
            for (int k = 0; k < F_; ++k) s += h1[k] * mw2[k * F_ + j];
            h2[j] = fmaxf(s, 0.0f);
        }
        for (int j = 0; j < F_; ++j) {
            float s = mb3[j];
            for (int k = 0; k < F_; ++k) s += h2[k] * mw3[k * F_ + j];
            float sc = fmaxf(s * 0.05f + sg, 0.0f) + 1e-9f;
            wsf[SINV_F + b * F_ + j] = 1.0f / sc;
            wsf[SLAM_F + b * F_ + j] = lamb_e * sc;
        }
    }
    if (tid == 50) {
        float lamb_e = expf(lamb[0]);
        float eps_e = expf(eps_om[0]);
        wsf[MISC_F + 0] = eps_e;
        wsf[MISC_F + 1] = 1.0f / (1.0f + lamb_e * (1.0f + eps_e));
    }
}

// ---------------- setup: fragment packing (grid-parallel; AFTER setup_math) ----------------
__global__ void setup_pack(const float* __restrict__ Wf, float* __restrict__ wsf)
{
    unsigned short* wsu = (unsigned short*)wsf;
    const int gtid = blockIdx.x * TPB + threadIdx.x;
    for (int i = gtid; i < 73728; i += gridDim.x * TPB) {
        if (i < 49152) {
            // pass-1 A frags: 24 mtiles. even = Wf (v-rows), odd = Qeq.Wf (y-rows)
            int j = i & 7, lane = (i >> 3) & 63;
            int t = i >> 9;                // 0..95
            int ks = t & 3, mtile = t >> 2;
            int rt = lane & 15, qq = lane >> 4;
            int c = ks * 32 + qq * 8 + j;
            int ft = mtile >> 1;
            int f = ft * 4 + (rt >> 2);
            int gl = rt & 3;
            float w;
            if ((mtile & 1) == 0) {
                w = Wf[(gl * F_ + f) * C_ + c];
            } else {
                w = 0.f;
                for (int g = 0; g < 4; ++g)
                    w += wsf[QEQN_F + f * 32 + gl * 4 + g] * Wf[(g * F_ + f) * C_ + c];
            }
            _Float16 hv = (_Float16)w;
            wsu[P1_U + ((mtile * 4 + ks) * 64 + lane) * 8 + j] = *(unsigned short*)&hv;
        } else {
            // pass-2 A frags: K=192, Wf^T only
            int ii = i - 49152;
            int j = ii & 7, lane = (ii >> 3) & 63;
            int t = ii >> 9;               // 0..47
            int ks = t % 6, cmt = t / 6;
            int m = lane & 15, qq = lane >> 4;
            int cch = cmt * 16 + m;
            int r = ks * 32 + qq * 8 + j;  // 0..191
            int f = r >> 2, g = r & 3;
            float w = Wf[(g * F_ + f) * C_ + cch];
            _Float16 hv = (_Float16)w;
            wsu[P2_U + ((cmt * 6 + ks) * 64 + lane) * 8 + j] = *(unsigned short*)&hv;
        }
    }
}

// Duchi-form l1-ball projection merged with the Moreau output:
//   theta = max(0, max_k (c_k - 1)/k)   (c_k = sum of k largest |v|)
//   o_g   = sign(v_g) * (eps*|v_g| + relu(|v_g| - theta))  ==  eps*v + proj(v)
// No sort network, no divide, no inside-branch (sum<=1 => theta=0 => identity).
__device__ __forceinline__ void actmerge(const float v[4], float eps, float o[4]) {
    float a0 = fabsf(v[0]), a1 = fabsf(v[1]), a2 = fabsf(v[2]), a3 = fabsf(v[3]);
    float lo01 = fminf(a0, a1), hi01 = fmaxf(a0, a1);
    float lo23 = fminf(a2, a3), hi23 = fmaxf(a2, a3);
    float c4 = (a0 + a1) + (a2 + a3);
    float mn1 = fminf(lo01, lo23);
    float mn2 = fminf(fmaxf(lo01, lo23), fminf(hi01, hi23));
    float c1 = fmaxf(hi01, hi23);
    float c3 = c4 - mn1;
    float c2 = c3 - mn2;
    float t1 = c1 - 1.0f;
    float t2 = (c2 - 1.0f) * 0.5f;
    float t3 = (c3 - 1.0f) * (1.0f / 3.0f);
    float t4 = (c4 - 1.0f) * 0.25f;
    float theta = fmaxf(fmaxf(fmaxf(t1, t2), fmaxf(t3, t4)), 0.0f);
    float aa[4] = {a0, a1, a2, a3};
#pragma unroll
    for (int g = 0; g < 4; ++g) {
        float r = fmaf(eps, aa[g], fmaxf(aa[g] - theta, 0.0f));
        o[g] = copysignf(r, v[g]);
    }
}

// ---------------- main: 32-pixel tile, 8 waves/block, 1024 blocks ----------------
// R2's occupancy regime (4 blk/CU, 8 waves/SIMD) + y-fold (p1 M=384) +
// Duchi-theta activation. p2 K=192 (no m2-fold) with r1c2 A-read-once.
// LDS ~24KB; launch_bounds(512,4) -> 64 VGPR (keep per-job pressure low:
// #pragma unroll 1 on p1 jobs; qs/invs/slam read per-job from LDS broadcasts).
__global__ __launch_bounds__(MTPB, 4) void mfoe_main(
    const float* __restrict__ xnoisy,
    const float* __restrict__ wsf,
    float* __restrict__ out,
    const int* __restrict__ n_iter_p)
{
    __shared__ __align__(16) _Float16 sXF[4096];    // [nt(2)][ks(4)][lane(64)][j(8)]
    __shared__ __align__(16) _Float16 sACT[6144];   // [nt(2)][ks(6)][lane(64)][j(8)]
    __shared__ __align__(16) float sQS[F_ * 16];    // SCALE*Qm[g][l] at [f][g*4+l]
    __shared__ __align__(16) float sISL[96];        // [0..47]=invs, [48..95]=slam

    const int tid = threadIdx.x;
    const int lane = tid & 63;
    const int wv = __builtin_amdgcn_readfirstlane(tid >> 6);   // SGPR wave id, 0..7
    const int n = lane & 15;
    const int q = lane >> 4;
    const int blk = blockIdx.x;
    const int b = blk >> 9;                 // 512 blocks per image
    const int pix0 = (blk & 511) << 5;      // 32 pixels per block

    const float* __restrict__ xin = xnoisy + b * (C_ * HW) + pix0;
    float* __restrict__ oimg = out + b * (C_ * HW) + pix0;
    const unsigned short* __restrict__ wsu = (const unsigned short*)wsf;
    const int niter = *n_iter_p;

    if (niter == 0) {
        for (int i = tid; i < C_ * 32; i += MTPB) {
            int p = i & 31, c = i >> 5;
            oimg[c * HW + p] = xin[c * HW + p];
        }
        return;
    }

    // stage x -> LDS f16 in fragment order
    for (int i = tid; i < C_ * 32; i += MTPB) {
        int p = i & 31, c = i >> 5;
        int idx = ((p >> 4) * 4 + (c >> 5)) * 512 + (((c >> 3) & 3) * 16 + (p & 15)) * 8 + (c & 7);
        sXF[idx] = (_Float16)xin[c * HW + p];
    }
    // stage qs (SCALE*Qm) and invs/slam
    for (int i = tid; i < F_ * 16; i += MTPB)
        sQS[i] = wsf[QEQN_F + (i >> 4) * 32 + 16 + (i & 15)];
    for (int i = tid; i < 96; i += MTPB) {
        if (i < 48) sISL[i] = wsf[SINV_F + b * F_ + i];
        else        sISL[i] = wsf[SLAM_F + b * F_ + (i - 48)];
    }

    // x_noisy anchor in registers (update layout: cmt = wv, nt 0..1)
    float xnr[8];
#pragma unroll
    for (int nt = 0; nt < 2; ++nt)
#pragma unroll
        for (int l = 0; l < 4; ++l)
            xnr[nt * 4 + l] = xin[(wv * 16 + q * 4 + l) * HW + nt * 16 + n];

    const float eps_e = wsf[MISC_F + 0];
    const float invden = wsf[MISC_F + 1];

    const half8* __restrict__ A1 = (const half8*)wsu;              // P1 frags
    const half8* __restrict__ A2 = (const half8*)(wsu + P2_U);     // P2 frags
    const half8* __restrict__ sXF8 = (const half8*)sXF;
    const half8* __restrict__ sACT8 = (const half8*)sACT;

    for (int it = 0; it < niter; ++it) {
        __syncthreads();   // x ready (and tables on iter 0)
        // ---- pass 1: 24 jobs (ft 0..11, nt 0..1), 3 per wave, low-pressure
#pragma unroll 1
        for (int jj = 0; jj < 3; ++jj) {
            const int grp = wv * 3 + jj;
            const int ft = grp >> 1;
            const int nt = grp & 1;
            floatx4 accv = (floatx4){0.f, 0.f, 0.f, 0.f};
            floatx4 accy = (floatx4){0.f, 0.f, 0.f, 0.f};
#pragma unroll
            for (int ks = 0; ks < 4; ++ks) {
                half8 aV = A1[((ft * 2 + 0) * 4 + ks) * 64 + lane];
                half8 aY = A1[((ft * 2 + 1) * 4 + ks) * 64 + lane];
                half8 bF = sXF8[(nt * 4 + ks) * 64 + lane];
                accv = __builtin_amdgcn_mfma_f32_16x16x32_f16(aV, bF, accv, 0, 0, 0);
                accy = __builtin_amdgcn_mfma_f32_16x16x32_f16(aY, bF, accy, 0, 0, 0);
            }
            // ---- activation: lane owns f = ft*4+q (broadcast LDS reads per q-group)
            const int f = ft * 4 + q;
            const float invs = sISL[f];
            const float slam = sISL[48 + f];
            float qs[16];
#pragma unroll
            for (int k = 0; k < 4; ++k)
                *(floatx4*)&qs[4 * k] = *(const floatx4*)&sQS[f * 16 + 4 * k];
            float v[4] = {accv[0] * invs, accv[1] * invs, accv[2] * invs, accv[3] * invs};
            float y[4] = {accy[0] * invs, accy[1] * invs, accy[2] * invs, accy[3] * invs};
            float uv[4]; actmerge(v, eps_e, uv);    // eps*v + proj(v)
            float m2[4]; actmerge(y, eps_e, m2);    // eps*y + proj(y)
            // gcc_l = sum_g qs[g*4+l] * m2[g]; act = (uv - gcc) * slam
            float a0 = (uv[0] - fmaf(qs[0], m2[0], fmaf(qs[4], m2[1],
                        fmaf(qs[8], m2[2], qs[12] * m2[3])))) * slam;
            float a1 = (uv[1] - fmaf(qs[1], m2[0], fmaf(qs[5], m2[1],
                        fmaf(qs[9], m2[2], qs[13] * m2[3])))) * slam;
            float a2 = (uv[2] - fmaf(qs[2], m2[0], fmaf(qs[6], m2[1],
                        fmaf(qs[10], m2[2], qs[14] * m2[3])))) * slam;
            float a3 = (uv[3] - fmaf(qs[3], m2[0], fmaf(qs[7], m2[1],
                        fmaf(qs[11], m2[2], qs[15] * m2[3])))) * slam;
            half4 av4;
            av4[0] = (_Float16)a0;
            av4[1] = (_Float16)a1;
            av4[2] = (_Float16)a2;
            av4[3] = (_Float16)a3;
            int aw = ((nt * 6 + (ft >> 1)) * 64 + ((ft & 1) * 2 + (q >> 1)) * 16 + n) * 8 + (q & 1) * 4;
            *(half4*)&sACT[aw] = av4;
        }
        __syncthreads();   // act ready; all pass-1 x reads done
        // ---- pass 2: cmt = wv, both nt, K=192; A loaded once per ks
        floatx4 acc20 = (floatx4){0.f, 0.f, 0.f, 0.f};
        floatx4 acc21 = (floatx4){0.f, 0.f, 0.f, 0.f};
#pragma unroll
        for (int ks = 0; ks < 6; ++ks) {
            half8 aF = A2[(wv * 6 + ks) * 64 + lane];
            half8 bA0 = sACT8[(0 * 6 + ks) * 64 + lane];
            half8 bA1 = sACT8[(1 * 6 + ks) * 64 + lane];
            acc20 = __builtin_amdgcn_mfma_f32_16x16x32_f16(aF, bA0, acc20, 0, 0, 0);
            acc21 = __builtin_amdgcn_mfma_f32_16x16x32_f16(aF, bA1, acc21, 0, 0, 0);
        }
        // ---- update: thread owns (cmt=wv, q, nt 0..1); x carried in sXF (f16)
        const bool last = (it == niter - 1);
#pragma unroll
        for (int nt = 0; nt < 2; ++nt) {
            floatx4 acc = nt ? acc21 : acc20;
            int p = nt * 16 + n;
            int xu = ((nt * 4 + (wv >> 1)) * 64 + ((wv & 1) * 2 + (q >> 1)) * 16 + n) * 8 + (q & 1) * 4;
            half4 xo4 = *(const half4*)&sXF[xu];
            half4 nx4;
#pragma unroll
            for (int l = 0; l < 4; ++l) {
                float xo = (float)xo4[l];
                float nx = xo - ((xo - xnr[nt * 4 + l]) + acc[l]) * invden;
                nx4[l] = (_Float16)nx;
                if (last) oimg[(wv * 16 + q * 4 + l) * HW + p] = nx;
            }
            *(half4*)&sXF[xu] = nx4;
        }
    }
}

extern "C" void kernel_launch(void* const* d_in, const int* in_sizes, int n_in,
                              void* d_out, int out_size, void* d_ws, size_t ws_size,
                              hipStream_t stream) {
    const float* x_noisy = (const float*)d_in[0];
    const float* sigma   = (const float*)d_in[1];
    const float* Qp      = (const float*)d_in[2];
    const float* taus_p  = (const float*)d_in[3];
    const float* lamb    = (const float*)d_in[4];
    const float* eps_om  = (const float*)d_in[5];
    const float* mw1     = (const float*)d_in[6];
    const float* mb1     = (const float*)d_in[7];
    const float* mw2     = (const float*)d_in[8];
    const float* mb2     = (const float*)d_in[9];
    const float* mw3     = (const float*)d_in[10];
    const float* mb3     = (const float*)d_in[11];
    const float* Wf      = (const float*)d_in[12];
    const int*   n_iter  = (const int*)d_in[13];
    float* out = (float*)d_out;
    float* ws  = (float*)d_ws;

    hipLaunchKernelGGL(setup_math, dim3(1), dim3(64), 0, stream,
                       sigma, Qp, taus_p, lamb, eps_om,
                       mw1, mb1, mw2, mb2, mw3, mb3, ws);
    hipLaunchKernelGGL(setup_pack, dim3(192), dim3(TPB), 0, stream, Wf, ws);
    hipLaunchKernelGGL(mfoe_main, dim3(1024), dim3(MTPB), 0, stream,
                       x_noisy, ws, out, n_iter);
}